// Round 1
// baseline (374.065 us; speedup 1.0000x reference)
//
#include <hip/hip_runtime.h>

#define B_ 4
#define N_ 4096
#define D_ 1536
#define H_ 512
#define K_ 8
#define M_ (B_*N_)          // 16384
#define R2_ 160000.0f       // 400^2

typedef __attribute__((ext_vector_type(8))) short bf16x8;
typedef __attribute__((ext_vector_type(4))) float f32x4;

__device__ __forceinline__ unsigned short f2bf(float f) {
  union { float f; unsigned u; } v; v.f = f;
  unsigned r = (v.u + 0x7FFFu + ((v.u >> 16) & 1u)) >> 16;
  return (unsigned short)r;
}
__device__ __forceinline__ float bf2f(unsigned short s) {
  union { unsigned u; float f; } v; v.u = ((unsigned)s) << 16; return v.f;
}

// ---------------- K0: anchor norms (clipped) ----------------
__global__ void k_anorm(const float* __restrict__ anchors, float* __restrict__ anorm) {
  int k = blockIdx.x; int lane = threadIdx.x;
  float s = 0.f;
  for (int i = lane; i < D_; i += 64) { float v = anchors[k*D_ + i]; s += v*v; }
  #pragma unroll
  for (int off = 32; off; off >>= 1) s += __shfl_down(s, off);
  if (lane == 0) anorm[k] = fmaxf(sqrtf(s), 1e-12f);
}

// ---------------- K0b: weight transpose + bf16 cast ----------------
// WfT[n*1536+k] = bf16(W_feat[k*512+n])
__global__ void k_wft(const float* __restrict__ W, unsigned short* __restrict__ WT) {
  int n = blockIdx.y; int k = blockIdx.x*256 + threadIdx.x;
  WT[(size_t)n*D_ + k] = f2bf(W[(size_t)k*H_ + n]);
}
// WgsT[n*1024+k] = bf16(k<512 ? W_gnn[k][n] : W_self[k-512][n])
__global__ void k_wgs(const float* __restrict__ Wg, const float* __restrict__ Ws,
                      unsigned short* __restrict__ WT) {
  int n = blockIdx.y; int k = blockIdx.x*256 + threadIdx.x;
  float v = (k < 512) ? Wg[(size_t)k*H_ + n] : Ws[(size_t)(k-512)*H_ + n];
  WT[(size_t)n*1024 + k] = f2bf(v);
}

// ---------------- K1: concept scores + images f32->bf16 cast ----------------
__global__ void k_concept_cast(const float* __restrict__ images,
                               const float* __restrict__ anchors,
                               const float* __restrict__ anorm,
                               unsigned short* __restrict__ imgs_bf,
                               float* __restrict__ out) {
  __shared__ float sc[4][K_];
  int tid = threadIdx.x;
  int lane = tid & 63, w = tid >> 6;
  int gm = blockIdx.x*4 + w;
  const float4* xrow = (const float4*)(images + (size_t)gm*D_);
  const float4* a4 = (const float4*)anchors;
  float dot[K_] = {};
  float nrm = 0.f;
  #pragma unroll
  for (int it = 0; it < 6; it++) {
    int j = lane + 64*it;
    float4 x = xrow[j];
    nrm += x.x*x.x + x.y*x.y + x.z*x.z + x.w*x.w;
    #pragma unroll
    for (int k = 0; k < K_; k++) {
      float4 a = a4[k*(D_/4) + j];
      dot[k] += x.x*a.x + x.y*a.y + x.z*a.z + x.w*a.w;
    }
    ushort4 s;
    s.x = f2bf(x.x); s.y = f2bf(x.y); s.z = f2bf(x.z); s.w = f2bf(x.w);
    *(ushort4*)&imgs_bf[(size_t)gm*D_ + (size_t)j*4] = s;
  }
  #pragma unroll
  for (int off = 32; off; off >>= 1) {
    nrm += __shfl_down(nrm, off);
    #pragma unroll
    for (int k = 0; k < K_; k++) dot[k] += __shfl_down(dot[k], off);
  }
  if (lane == 0) {
    float inv = 1.0f / fmaxf(sqrtf(nrm), 1e-12f);
    #pragma unroll
    for (int k = 0; k < K_; k++) sc[w][k] = dot[k] * inv / anorm[k];
  }
  __syncthreads();
  if (tid < K_) {
    float s = sc[0][tid] + sc[1][tid] + sc[2][tid] + sc[3][tid];
    int b = blockIdx.x >> 10;   // 1024 blocks per graph
    atomicAdd(out + b*(H_+K_) + H_ + tid, s * (1.0f/N_));
  }
}

// ---------------- GEMM: C(16384 x 512) = A(16384 x Kdim) @ BT^T ----------------
// BT is (512 x Kdim) row-major (i.e. B transposed), bf16.
// mode 0: epilogue feat = acc + b_feat + pos@W_pos -> bf16 into AB cols [512:1024)
// mode 1: epilogue relu + per-column mean over each graph -> atomicAdd into out
#define BM 128
#define BN 128
#define BK 32
#define ST 40   // LDS row stride in bf16 elems (pad 32->40, keeps 16B alignment)

__global__ void k_gemm(const unsigned short* __restrict__ A,
                       const unsigned short* __restrict__ BT,
                       int Kdim, int mode,
                       const float* __restrict__ bias,
                       const float* __restrict__ Wpos,
                       const float* __restrict__ positions,
                       unsigned short* __restrict__ AB,
                       float* __restrict__ out) {
  __shared__ unsigned short As[BM*ST];
  __shared__ unsigned short Bs[BN*ST];
  __shared__ float colsum[BN];
  int tid = threadIdx.x;
  int lane = tid & 63, wv = tid >> 6;
  int wm = wv >> 1, wn = wv & 1;
  int l15 = lane & 15, quad = lane >> 4;
  int bx = blockIdx.x;
  int bm = bx & 127, bn = bx >> 7;       // 128 M-tiles x 4 N-tiles
  int m0 = bm*BM, n0 = bn*BN;

  f32x4 acc[4][4] = {};

  int rt = tid >> 1, kh = tid & 1;
  const unsigned short* gA = A + (size_t)(m0 + rt)*Kdim + kh*16;
  const unsigned short* gB = BT + (size_t)(n0 + rt)*Kdim + kh*16;
  unsigned short* lA = &As[rt*ST + kh*16];
  unsigned short* lB = &Bs[rt*ST + kh*16];

  int nk = Kdim / BK;
  for (int kt = 0; kt < nk; kt++) {
    __syncthreads();
    uint4 a0 = *(const uint4*)(gA);
    uint4 a1 = *(const uint4*)(gA + 8);
    uint4 b0 = *(const uint4*)(gB);
    uint4 b1 = *(const uint4*)(gB + 8);
    *(uint4*)lA = a0; *(uint4*)(lA + 8) = a1;
    *(uint4*)lB = b0; *(uint4*)(lB + 8) = b1;
    gA += BK; gB += BK;
    __syncthreads();

    bf16x8 aF[4], bF[4];
    #pragma unroll
    for (int f = 0; f < 4; f++)
      aF[f] = *(const bf16x8*)&As[(wm*64 + f*16 + l15)*ST + quad*8];
    #pragma unroll
    for (int f = 0; f < 4; f++)
      bF[f] = *(const bf16x8*)&Bs[(wn*64 + f*16 + l15)*ST + quad*8];
    #pragma unroll
    for (int mi = 0; mi < 4; mi++)
      #pragma unroll
      for (int ni = 0; ni < 4; ni++)
        acc[mi][ni] = __builtin_amdgcn_mfma_f32_16x16x32_bf16(aF[mi], bF[ni], acc[mi][ni], 0, 0, 0);
  }

  if (mode == 0) {
    #pragma unroll
    for (int ni = 0; ni < 4; ni++) {
      int gh = n0 + wn*64 + ni*16 + l15;
      float bz = bias[gh];
      float w0 = Wpos[gh];
      float w1 = Wpos[H_ + gh];
      #pragma unroll
      for (int mi = 0; mi < 4; mi++) {
        #pragma unroll
        for (int r = 0; r < 4; r++) {
          int gm = m0 + wm*64 + mi*16 + quad*4 + r;
          float px = positions[(size_t)gm*2];
          float py = positions[(size_t)gm*2 + 1];
          float v = acc[mi][ni][r] + bz + px*w0 + py*w1;
          AB[(size_t)gm*1024 + 512 + gh] = f2bf(v);
        }
      }
    }
  } else {
    if (tid < BN) colsum[tid] = 0.f;
    __syncthreads();
    #pragma unroll
    for (int ni = 0; ni < 4; ni++) {
      float s = 0.f;
      #pragma unroll
      for (int mi = 0; mi < 4; mi++) {
        #pragma unroll
        for (int r = 0; r < 4; r++) s += fmaxf(acc[mi][ni][r], 0.f);
      }
      s += __shfl_down(s, 32);
      s += __shfl_down(s, 16);
      if (quad == 0) atomicAdd(&colsum[wn*64 + ni*16 + l15], s);
    }
    __syncthreads();
    if (tid < BN) {
      int b = m0 >> 12;
      atomicAdd(out + b*(H_+K_) + n0 + tid, colsum[tid] * (1.0f/N_));
    }
  }
}

// ---------------- K3: radius graph + mean aggregation of relu(feat) ----------------
__global__ void k_aggregate(const float* __restrict__ positions,
                            unsigned short* __restrict__ AB) {
  __shared__ unsigned short nlist[N_];
  __shared__ int cnt;
  int gm = blockIdx.x;
  int b = gm >> 12, i = gm & 4095;
  int tid = threadIdx.x;
  if (tid == 0) cnt = 0;
  __syncthreads();
  const float* pos = positions + (size_t)b*N_*2;
  float xi = pos[(size_t)i*2], yi = pos[(size_t)i*2 + 1];
  for (int j = tid; j < N_; j += 256) {
    float dx = pos[(size_t)j*2] - xi;
    float dy = pos[(size_t)j*2 + 1] - yi;
    float d2 = dx*dx + dy*dy;
    if (d2 < R2_ && j != i) {
      int p = atomicAdd(&cnt, 1);
      nlist[p] = (unsigned short)j;
    }
  }
  __syncthreads();
  int deg = cnt;
  float inv = 1.0f / (float)(deg > 1 ? deg : 1);
  float a0 = 0.f, a1 = 0.f;
  const unsigned short* featbase = AB + (size_t)(b << 12)*1024 + 512 + tid*2;
  for (int n = 0; n < deg; n++) {
    int j = nlist[n];
    unsigned v = *(const unsigned*)(featbase + (size_t)j*1024);
    a0 += fmaxf(bf2f((unsigned short)(v & 0xFFFFu)), 0.f);
    a1 += fmaxf(bf2f((unsigned short)(v >> 16)), 0.f);
  }
  unsigned o0 = f2bf(a0*inv), o1 = f2bf(a1*inv);
  *(unsigned*)(AB + (size_t)gm*1024 + tid*2) = (o1 << 16) | o0;
}

extern "C" void kernel_launch(void* const* d_in, const int* in_sizes, int n_in,
                              void* d_out, int out_size, void* d_ws, size_t ws_size,
                              hipStream_t stream) {
  const float* images    = (const float*)d_in[0];
  const float* positions = (const float*)d_in[1];
  const float* W_feat    = (const float*)d_in[2];
  const float* b_feat    = (const float*)d_in[3];
  const float* W_pos     = (const float*)d_in[4];
  const float* W_gnn     = (const float*)d_in[5];
  const float* W_self    = (const float*)d_in[6];
  const float* anchors   = (const float*)d_in[7];
  float* out = (float*)d_out;

  char* ws = (char*)d_ws;
  unsigned short* imgs_bf = (unsigned short*)ws;                     // 16384*1536*2 = 50331648
  unsigned short* AB      = (unsigned short*)(ws + 50331648);        // 16384*1024*2 = 33554432
  unsigned short* WfT     = (unsigned short*)(ws + 83886080);        // 512*1536*2  = 1572864
  unsigned short* WgsT    = (unsigned short*)(ws + 85458944);        // 512*1024*2  = 1048576
  float*          anorm   = (float*)(ws + 86507520);                 // 8*4

  hipMemsetAsync(d_out, 0, sizeof(float)*B_*(H_+K_), stream);
  k_anorm<<<K_, 64, 0, stream>>>(anchors, anorm);
  k_wft<<<dim3(D_/256, H_), 256, 0, stream>>>(W_feat, WfT);
  k_wgs<<<dim3(1024/256, H_), 256, 0, stream>>>(W_gnn, W_self, WgsT);
  k_concept_cast<<<M_/4, 256, 0, stream>>>(images, anchors, anorm, imgs_bf, out);
  k_gemm<<<512, 256, 0, stream>>>(imgs_bf, WfT, D_, 0, b_feat, W_pos, positions, AB, out);
  k_aggregate<<<M_, 256, 0, stream>>>(positions, AB);
  k_gemm<<<512, 256, 0, stream>>>(AB, WgsT, 1024, 1, nullptr, nullptr, nullptr, AB, out);
}

// Round 2
// 338.178 us; speedup vs baseline: 1.1061x; 1.1061x over previous
//
#include <hip/hip_runtime.h>

#define B_ 4
#define N_ 4096
#define D_ 1536
#define H_ 512
#define K_ 8
#define M_ (B_*N_)          // 16384
#define R2_ 160000.0f       // 400^2

typedef __attribute__((ext_vector_type(8))) short bf16x8;
typedef __attribute__((ext_vector_type(4))) float f32x4;

__device__ __forceinline__ unsigned short f2bf(float f) {
  union { float f; unsigned u; } v; v.f = f;
  unsigned r = (v.u + 0x7FFFu + ((v.u >> 16) & 1u)) >> 16;
  return (unsigned short)r;
}
__device__ __forceinline__ float bf2f(unsigned short s) {
  union { unsigned u; float f; } v; v.u = ((unsigned)s) << 16; return v.f;
}

typedef const __attribute__((address_space(1))) unsigned int gas_u32;
typedef __attribute__((address_space(3))) unsigned int las_u32;
__device__ __forceinline__ void gl_lds16(const unsigned short* g, unsigned short* l) {
  __builtin_amdgcn_global_load_lds((gas_u32*)g, (las_u32*)l, 16, 0, 0);
}

// ---------------- K0: anchor norms (clipped) ----------------
__global__ void k_anorm(const float* __restrict__ anchors, float* __restrict__ anorm) {
  int k = blockIdx.x; int lane = threadIdx.x;
  float s = 0.f;
  for (int i = lane; i < D_; i += 64) { float v = anchors[k*D_ + i]; s += v*v; }
  #pragma unroll
  for (int off = 32; off; off >>= 1) s += __shfl_down(s, off);
  if (lane == 0) anorm[k] = fmaxf(sqrtf(s), 1e-12f);
}

// ---------------- K0b: coalesced LDS transpose, f32 (Krows x 512) -> bf16 (512 x outStride) ----------------
__global__ void k_transpose(const float* __restrict__ W, unsigned short* __restrict__ WT,
                            int Krows, int outStride, int outOff) {
  __shared__ float t[64][65];
  int bx = blockIdx.x;            // n-tile (512/64 = 8)
  int by = blockIdx.y;            // k-tile (Krows/64)
  int tid = threadIdx.x;
  int tx = tid & 63, ty = tid >> 6;
  #pragma unroll
  for (int r = 0; r < 64; r += 4)
    t[ty + r][tx] = W[(size_t)(by*64 + ty + r)*H_ + bx*64 + tx];
  __syncthreads();
  #pragma unroll
  for (int r = 0; r < 64; r += 4) {
    int n = bx*64 + ty + r;
    WT[(size_t)n*outStride + outOff + by*64 + tx] = f2bf(t[tx][ty + r]);
  }
}

// ---------------- K1: concept scores + images f32->bf16 cast (LDS-staged anchors) ----------------
__global__ __launch_bounds__(256) void k_concept_cast(
    const float* __restrict__ images, const float* __restrict__ anchors,
    const float* __restrict__ anorm, unsigned short* __restrict__ imgs_bf,
    float* __restrict__ out) {
  __shared__ float sA[K_*D_];     // 48 KB
  __shared__ float sc[4][K_];
  int tid = threadIdx.x, lane = tid & 63, w = tid >> 6;
  {
    const float4* a4 = (const float4*)anchors;
    float4* sA4 = (float4*)sA;
    #pragma unroll
    for (int i = 0; i < 12; i++) sA4[tid + 256*i] = a4[tid + 256*i];
  }
  __syncthreads();
  float acc_k[K_] = {};
  for (int r = 0; r < 8; r++) {
    int gm = blockIdx.x*32 + w*8 + r;
    const float4* xrow = (const float4*)(images + (size_t)gm*D_);
    float nrm = 0.f; float dot[K_] = {};
    #pragma unroll
    for (int it = 0; it < 6; it++) {
      int j = lane + 64*it;
      float4 x = xrow[j];
      nrm += x.x*x.x + x.y*x.y + x.z*x.z + x.w*x.w;
      #pragma unroll
      for (int k = 0; k < K_; k++) {
        float4 a = *(const float4*)&sA[(size_t)(k*384 + j)*4];
        dot[k] += x.x*a.x + x.y*a.y + x.z*a.z + x.w*a.w;
      }
      ushort4 s;
      s.x = f2bf(x.x); s.y = f2bf(x.y); s.z = f2bf(x.z); s.w = f2bf(x.w);
      *(ushort4*)&imgs_bf[(size_t)gm*D_ + (size_t)j*4] = s;
    }
    #pragma unroll
    for (int off = 32; off; off >>= 1) {
      nrm += __shfl_down(nrm, off);
      #pragma unroll
      for (int k = 0; k < K_; k++) dot[k] += __shfl_down(dot[k], off);
    }
    if (lane == 0) {
      float inv = 1.0f / fmaxf(sqrtf(nrm), 1e-12f);
      #pragma unroll
      for (int k = 0; k < K_; k++) acc_k[k] += dot[k] * inv / anorm[k];
    }
  }
  if (lane == 0) {
    #pragma unroll
    for (int k = 0; k < K_; k++) sc[w][k] = acc_k[k];
  }
  __syncthreads();
  if (tid < K_) {
    float s = sc[0][tid] + sc[1][tid] + sc[2][tid] + sc[3][tid];
    int b = blockIdx.x >> 7;    // 128 blocks per graph
    atomicAdd(out + b*(H_+K_) + H_ + tid, s * (1.0f/N_));
  }
}

// ---------------- GEMM: C(16384 x 512) = A(16384 x Kdim) @ BT^T, m97-style staging ----------------
#define BM 128
#define BN 128
#define BK 32

__global__ __launch_bounds__(256) void k_gemm(
    const unsigned short* __restrict__ A, const unsigned short* __restrict__ BT,
    int Kdim, int mode, const float* __restrict__ bias, const float* __restrict__ Wpos,
    const float* __restrict__ positions, unsigned short* __restrict__ AB,
    float* __restrict__ out) {
  __shared__ unsigned short As[BM*BK];   // 8 KB, row-major stride 32 (unpadded: DMA layout)
  __shared__ unsigned short Bs[BN*BK];
  __shared__ float colsum[BN];
  int tid = threadIdx.x;
  int lane = tid & 63, wv = tid >> 6;
  int wm = wv >> 1, wn = wv & 1;
  int l15 = lane & 15, quad = lane >> 4;
  int bx = blockIdx.x;
  int bm = bx & 127, bn = bx >> 7;       // 128 M-tiles x 4 N-tiles
  int m0 = bm*BM, n0 = bn*BN;

  f32x4 acc[4][4] = {};

  // DMA staging: wave wv covers 16-row chunks c=2*wv, 2*wv+1 for both A and B.
  int c = wv*2;
  int rowc = (lane >> 2), seg = lane & 3;
  const unsigned short* gA0 = A  + (size_t)(m0 + c*16 + rowc)*Kdim + seg*8;
  const unsigned short* gA1 = gA0 + (size_t)16*Kdim;
  const unsigned short* gB0 = BT + (size_t)(n0 + c*16 + rowc)*Kdim + seg*8;
  const unsigned short* gB1 = gB0 + (size_t)16*Kdim;
  unsigned short* lA0 = As + c*512;  // wave-uniform LDS base; DMA scatters lane*16B
  unsigned short* lA1 = lA0 + 512;
  unsigned short* lB0 = Bs + c*512;
  unsigned short* lB1 = lB0 + 512;

  int nk = Kdim / BK;
  for (int kt = 0; kt < nk; kt++) {
    __syncthreads();
    gl_lds16(gA0, lA0); gl_lds16(gA1, lA1);
    gl_lds16(gB0, lB0); gl_lds16(gB1, lB1);
    gA0 += BK; gA1 += BK; gB0 += BK; gB1 += BK;
    __syncthreads();

    bf16x8 aF[4], bF[4];
    #pragma unroll
    for (int f = 0; f < 4; f++)
      aF[f] = *(const bf16x8*)&As[(wm*64 + f*16 + l15)*BK + quad*8];
    #pragma unroll
    for (int f = 0; f < 4; f++)
      bF[f] = *(const bf16x8*)&Bs[(wn*64 + f*16 + l15)*BK + quad*8];
    #pragma unroll
    for (int mi = 0; mi < 4; mi++)
      #pragma unroll
      for (int ni = 0; ni < 4; ni++)
        acc[mi][ni] = __builtin_amdgcn_mfma_f32_16x16x32_bf16(aF[mi], bF[ni], acc[mi][ni], 0, 0, 0);
  }

  if (mode == 0) {
    #pragma unroll
    for (int ni = 0; ni < 4; ni++) {
      int gh = n0 + wn*64 + ni*16 + l15;
      float bz = bias[gh];
      float w0 = Wpos[gh];
      float w1 = Wpos[H_ + gh];
      #pragma unroll
      for (int mi = 0; mi < 4; mi++) {
        #pragma unroll
        for (int r = 0; r < 4; r++) {
          int gm = m0 + wm*64 + mi*16 + quad*4 + r;
          float px = positions[(size_t)gm*2];
          float py = positions[(size_t)gm*2 + 1];
          float v = acc[mi][ni][r] + bz + px*w0 + py*w1;
          AB[(size_t)gm*1024 + 512 + gh] = f2bf(v);
        }
      }
    }
  } else {
    if (tid < BN) colsum[tid] = 0.f;
    __syncthreads();
    #pragma unroll
    for (int ni = 0; ni < 4; ni++) {
      float s = 0.f;
      #pragma unroll
      for (int mi = 0; mi < 4; mi++) {
        #pragma unroll
        for (int r = 0; r < 4; r++) s += fmaxf(acc[mi][ni][r], 0.f);
      }
      s += __shfl_down(s, 32);
      s += __shfl_down(s, 16);
      if (quad == 0) atomicAdd(&colsum[wn*64 + ni*16 + l15], s);
    }
    __syncthreads();
    if (tid < BN) {
      int b = m0 >> 12;
      atomicAdd(out + b*(H_+K_) + n0 + tid, colsum[tid] * (1.0f/N_));
    }
  }
}

// ---------------- K3: radius graph + mean aggregation of relu(feat) ----------------
__global__ void k_aggregate(const float* __restrict__ positions,
                            unsigned short* __restrict__ AB) {
  __shared__ unsigned short nlist[N_];
  __shared__ int cnt;
  int gm = blockIdx.x;
  int b = gm >> 12, i = gm & 4095;
  int tid = threadIdx.x;
  if (tid == 0) cnt = 0;
  __syncthreads();
  const float* pos = positions + (size_t)b*N_*2;
  float xi = pos[(size_t)i*2], yi = pos[(size_t)i*2 + 1];
  for (int j = tid; j < N_; j += 256) {
    float dx = pos[(size_t)j*2] - xi;
    float dy = pos[(size_t)j*2 + 1] - yi;
    float d2 = dx*dx + dy*dy;
    if (d2 < R2_ && j != i) {
      int p = atomicAdd(&cnt, 1);
      nlist[p] = (unsigned short)j;
    }
  }
  __syncthreads();
  int deg = cnt;
  float inv = 1.0f / (float)(deg > 1 ? deg : 1);
  float a0 = 0.f, a1 = 0.f;
  const unsigned short* featbase = AB + (size_t)(b << 12)*1024 + 512 + tid*2;
  for (int n = 0; n < deg; n++) {
    int j = nlist[n];
    unsigned v = *(const unsigned*)(featbase + (size_t)j*1024);
    a0 += fmaxf(bf2f((unsigned short)(v & 0xFFFFu)), 0.f);
    a1 += fmaxf(bf2f((unsigned short)(v >> 16)), 0.f);
  }
  unsigned o0 = f2bf(a0*inv), o1 = f2bf(a1*inv);
  *(unsigned*)(AB + (size_t)gm*1024 + tid*2) = (o1 << 16) | o0;
}

extern "C" void kernel_launch(void* const* d_in, const int* in_sizes, int n_in,
                              void* d_out, int out_size, void* d_ws, size_t ws_size,
                              hipStream_t stream) {
  const float* images    = (const float*)d_in[0];
  const float* positions = (const float*)d_in[1];
  const float* W_feat    = (const float*)d_in[2];
  const float* b_feat    = (const float*)d_in[3];
  const float* W_pos     = (const float*)d_in[4];
  const float* W_gnn     = (const float*)d_in[5];
  const float* W_self    = (const float*)d_in[6];
  const float* anchors   = (const float*)d_in[7];
  float* out = (float*)d_out;

  char* ws = (char*)d_ws;
  unsigned short* imgs_bf = (unsigned short*)ws;                     // 16384*1536*2 = 50331648
  unsigned short* AB      = (unsigned short*)(ws + 50331648);        // 16384*1024*2 = 33554432
  unsigned short* WfT     = (unsigned short*)(ws + 83886080);        // 512*1536*2  = 1572864
  unsigned short* WgsT    = (unsigned short*)(ws + 85458944);        // 512*1024*2  = 1048576
  float*          anorm   = (float*)(ws + 86507520);                 // 8*4

  hipMemsetAsync(d_out, 0, sizeof(float)*B_*(H_+K_), stream);
  k_anorm<<<K_, 64, 0, stream>>>(anchors, anorm);
  k_transpose<<<dim3(8, 24), 256, 0, stream>>>(W_feat, WfT, D_, D_, 0);
  k_transpose<<<dim3(8, 8), 256, 0, stream>>>(W_gnn,  WgsT, H_, 1024, 0);
  k_transpose<<<dim3(8, 8), 256, 0, stream>>>(W_self, WgsT, H_, 1024, 512);
  k_concept_cast<<<M_/32, 256, 0, stream>>>(images, anchors, anorm, imgs_bf, out);
  k_gemm<<<512, 256, 0, stream>>>(imgs_bf, WfT, D_, 0, b_feat, W_pos, positions, AB, out);
  k_aggregate<<<M_, 256, 0, stream>>>(positions, AB);
  k_gemm<<<512, 256, 0, stream>>>(AB, WgsT, 1024, 1, nullptr, nullptr, nullptr, AB, out);
}

// Round 3
// 318.185 us; speedup vs baseline: 1.1756x; 1.0628x over previous
//
#include <hip/hip_runtime.h>

#define B_ 4
#define N_ 4096
#define D_ 1536
#define H_ 512
#define K_ 8
#define M_ (B_*N_)          // 16384
#define R2_ 160000.0f       // 400^2
#define CAP 192             // max neighbors tracked per node (Poisson mean ~32)

typedef __attribute__((ext_vector_type(8))) short bf16x8;
typedef __attribute__((ext_vector_type(4))) float f32x4;

__device__ __forceinline__ unsigned short f2bf(float f) {
  union { float f; unsigned u; } v; v.f = f;
  unsigned r = (v.u + 0x7FFFu + ((v.u >> 16) & 1u)) >> 16;
  return (unsigned short)r;
}

typedef const __attribute__((address_space(1))) unsigned int gas_u32;
typedef __attribute__((address_space(3))) unsigned int las_u32;
__device__ __forceinline__ void gl_lds16(const unsigned short* g, unsigned short* l) {
  __builtin_amdgcn_global_load_lds((gas_u32*)g, (las_u32*)l, 16, 0, 0);
}

// ---------------- K0: prep — anchor norms + all weight transposes (one launch) ----------
// grid (8, 41): by<24 -> W_feat tile; 24..31 -> W_gnn; 32..39 -> W_self; 40 -> anorm
__global__ __launch_bounds__(256) void k_prep(
    const float* __restrict__ Wf, const float* __restrict__ Wg, const float* __restrict__ Ws,
    const float* __restrict__ anchors, unsigned short* __restrict__ WfT,
    unsigned short* __restrict__ WgsT, float* __restrict__ anorm) {
  __shared__ float t[64][65];
  __shared__ float red[4];
  int bx = blockIdx.x, by = blockIdx.y, tid = threadIdx.x;
  if (by == 40) {
    int k = bx;
    float s = 0.f;
    for (int i = tid; i < D_; i += 256) { float v = anchors[k*D_ + i]; s += v*v; }
    #pragma unroll
    for (int off = 32; off; off >>= 1) s += __shfl_down(s, off);
    if ((tid & 63) == 0) red[tid >> 6] = s;
    __syncthreads();
    if (tid == 0) anorm[k] = fmaxf(sqrtf(red[0]+red[1]+red[2]+red[3]), 1e-12f);
    return;
  }
  const float* W; unsigned short* WT; int kt, outStride, outOff;
  if (by < 24)      { W = Wf; WT = WfT;  kt = by;      outStride = D_;   outOff = 0; }
  else if (by < 32) { W = Wg; WT = WgsT; kt = by - 24; outStride = 1024; outOff = 0; }
  else              { W = Ws; WT = WgsT; kt = by - 32; outStride = 1024; outOff = 512; }
  int tx = tid & 63, ty = tid >> 6;
  #pragma unroll
  for (int r = 0; r < 64; r += 4)
    t[ty + r][tx] = W[(size_t)(kt*64 + ty + r)*H_ + bx*64 + tx];
  __syncthreads();
  #pragma unroll
  for (int r = 0; r < 64; r += 4) {
    int n = bx*64 + ty + r;
    WT[(size_t)n*outStride + outOff + kt*64 + tx] = f2bf(t[tx][ty + r]);
  }
}

// ---------------- K1: concept scores + images f32->bf16 cast (LDS-staged anchors) ----------------
__global__ __launch_bounds__(256) void k_concept_cast(
    const float* __restrict__ images, const float* __restrict__ anchors,
    const float* __restrict__ anorm, unsigned short* __restrict__ imgs_bf,
    float* __restrict__ out) {
  __shared__ float sA[K_*D_];     // 48 KB
  __shared__ float sc[4][K_];
  int tid = threadIdx.x, lane = tid & 63, w = tid >> 6;
  {
    const float4* a4 = (const float4*)anchors;
    float4* sA4 = (float4*)sA;
    #pragma unroll
    for (int i = 0; i < 12; i++) sA4[tid + 256*i] = a4[tid + 256*i];
  }
  __syncthreads();
  float acc_k[K_] = {};
  for (int r = 0; r < 8; r++) {
    int gm = blockIdx.x*32 + w*8 + r;
    const float4* xrow = (const float4*)(images + (size_t)gm*D_);
    float nrm = 0.f; float dot[K_] = {};
    #pragma unroll
    for (int it = 0; it < 6; it++) {
      int j = lane + 64*it;
      float4 x = xrow[j];
      nrm += x.x*x.x + x.y*x.y + x.z*x.z + x.w*x.w;
      #pragma unroll
      for (int k = 0; k < K_; k++) {
        float4 a = *(const float4*)&sA[(size_t)(k*384 + j)*4];
        dot[k] += x.x*a.x + x.y*a.y + x.z*a.z + x.w*a.w;
      }
      ushort4 s;
      s.x = f2bf(x.x); s.y = f2bf(x.y); s.z = f2bf(x.z); s.w = f2bf(x.w);
      *(ushort4*)&imgs_bf[(size_t)gm*D_ + (size_t)j*4] = s;
    }
    #pragma unroll
    for (int off = 32; off; off >>= 1) {
      nrm += __shfl_down(nrm, off);
      #pragma unroll
      for (int k = 0; k < K_; k++) dot[k] += __shfl_down(dot[k], off);
    }
    if (lane == 0) {
      float inv = 1.0f / fmaxf(sqrtf(nrm), 1e-12f);
      #pragma unroll
      for (int k = 0; k < K_; k++) acc_k[k] += dot[k] * inv / anorm[k];
    }
  }
  if (lane == 0) {
    #pragma unroll
    for (int k = 0; k < K_; k++) sc[w][k] = acc_k[k];
  }
  __syncthreads();
  if (tid < K_) {
    float s = sc[0][tid] + sc[1][tid] + sc[2][tid] + sc[3][tid];
    int b = blockIdx.x >> 7;    // 128 blocks per graph
    atomicAdd(out + b*(H_+K_) + H_ + tid, s * (1.0f/N_));
  }
}

// ---------------- GEMM: C(16384 x 512) = A(16384 x Kdim) @ BT^T, m97-style staging ----------------
#define BM 128
#define BN 128
#define BK 32

__global__ __launch_bounds__(256) void k_gemm(
    const unsigned short* __restrict__ A, const unsigned short* __restrict__ BT,
    int Kdim, int mode, const float* __restrict__ bias, const float* __restrict__ Wpos,
    const float* __restrict__ positions, unsigned short* __restrict__ AB,
    float* __restrict__ out) {
  __shared__ unsigned short As[BM*BK];   // 8 KB, row-major stride 32 (unpadded: DMA layout)
  __shared__ unsigned short Bs[BN*BK];
  __shared__ float colsum[BN];
  int tid = threadIdx.x;
  int lane = tid & 63, wv = tid >> 6;
  int wm = wv >> 1, wn = wv & 1;
  int l15 = lane & 15, quad = lane >> 4;
  int bx = blockIdx.x;
  // bn-major: the 4 blocks sharing an A-tile are temporally adjacent -> L3 absorbs refetch
  int bm = bx >> 2, bn = bx & 3;
  int m0 = bm*BM, n0 = bn*BN;

  f32x4 acc[4][4] = {};

  int c = wv*2;
  int rowc = (lane >> 2), seg = lane & 3;
  const unsigned short* gA0 = A  + (size_t)(m0 + c*16 + rowc)*Kdim + seg*8;
  const unsigned short* gA1 = gA0 + (size_t)16*Kdim;
  const unsigned short* gB0 = BT + (size_t)(n0 + c*16 + rowc)*Kdim + seg*8;
  const unsigned short* gB1 = gB0 + (size_t)16*Kdim;
  unsigned short* lA0 = As + c*512;  // wave-uniform LDS base; DMA scatters lane*16B
  unsigned short* lA1 = lA0 + 512;
  unsigned short* lB0 = Bs + c*512;
  unsigned short* lB1 = lB0 + 512;

  int nk = Kdim / BK;
  for (int kt = 0; kt < nk; kt++) {
    __syncthreads();
    gl_lds16(gA0, lA0); gl_lds16(gA1, lA1);
    gl_lds16(gB0, lB0); gl_lds16(gB1, lB1);
    gA0 += BK; gA1 += BK; gB0 += BK; gB1 += BK;
    __syncthreads();

    bf16x8 aF[4], bF[4];
    #pragma unroll
    for (int f = 0; f < 4; f++)
      aF[f] = *(const bf16x8*)&As[(wm*64 + f*16 + l15)*BK + quad*8];
    #pragma unroll
    for (int f = 0; f < 4; f++)
      bF[f] = *(const bf16x8*)&Bs[(wn*64 + f*16 + l15)*BK + quad*8];
    #pragma unroll
    for (int mi = 0; mi < 4; mi++)
      #pragma unroll
      for (int ni = 0; ni < 4; ni++)
        acc[mi][ni] = __builtin_amdgcn_mfma_f32_16x16x32_bf16(aF[mi], bF[ni], acc[mi][ni], 0, 0, 0);
  }

  if (mode == 0) {
    #pragma unroll
    for (int ni = 0; ni < 4; ni++) {
      int gh = n0 + wn*64 + ni*16 + l15;
      float bz = bias[gh];
      float w0 = Wpos[gh];
      float w1 = Wpos[H_ + gh];
      #pragma unroll
      for (int mi = 0; mi < 4; mi++) {
        #pragma unroll
        for (int r = 0; r < 4; r++) {
          int gm = m0 + wm*64 + mi*16 + quad*4 + r;
          float px = positions[(size_t)gm*2];
          float py = positions[(size_t)gm*2 + 1];
          float v = acc[mi][ni][r] + bz + px*w0 + py*w1;
          AB[(size_t)gm*1024 + 512 + gh] = f2bf(v);
        }
      }
    }
  } else {
    if (tid < BN) colsum[tid] = 0.f;
    __syncthreads();
    #pragma unroll
    for (int ni = 0; ni < 4; ni++) {
      float s = 0.f;
      #pragma unroll
      for (int mi = 0; mi < 4; mi++) {
        #pragma unroll
        for (int r = 0; r < 4; r++) s += fmaxf(acc[mi][ni][r], 0.f);
      }
      s += __shfl_down(s, 32);
      s += __shfl_down(s, 16);
      if (quad == 0) atomicAdd(&colsum[wn*64 + ni*16 + l15], s);
    }
    __syncthreads();
    if (tid < BN) {
      int b = m0 >> 12;
      atomicAdd(out + b*(H_+K_) + n0 + tid, colsum[tid] * (1.0f/N_));
    }
  }
}

// ---------------- K3: radius graph + mean aggregation, 16 dests/block, XCD-swizzled ----------------
__global__ __launch_bounds__(256) void k_aggregate(const float* __restrict__ positions,
                                                   unsigned short* __restrict__ AB) {
  __shared__ unsigned short nlist[16*CAP];
  __shared__ int cnt[16];
  __shared__ float sdx[16], sdy[16];
  int blk = blockIdx.x;                 // 0..1023
  int xcd = blk & 7;
  int b = xcd >> 1;                     // graph b pinned to XCDs {2b, 2b+1}
  int sub = ((blk >> 3) << 1) | (xcd & 1);   // 0..255
  int dest0 = sub * 16;                 // first dest node within graph
  int tid = threadIdx.x, lane = tid & 63, w = tid >> 6;
  const float2* p2 = (const float2*)(positions + (size_t)b*N_*2);
  if (tid < 16) {
    cnt[tid] = 0;
    float2 pd = p2[dest0 + tid];
    sdx[tid] = pd.x; sdy[tid] = pd.y;
  }
  __syncthreads();
  // phase 1: one scan of positions, 16 dests tested per src point
  for (int it = 0; it < 16; it++) {
    int j = tid + 256*it;
    float2 pj = p2[j];
    #pragma unroll
    for (int d = 0; d < 16; d++) {
      float dx = pj.x - sdx[d], dy = pj.y - sdy[d];
      if (dx*dx + dy*dy < R2_ && j != dest0 + d) {
        int p = atomicAdd(&cnt[d], 1);
        if (p < CAP) nlist[d*CAP + p] = (unsigned short)j;
      }
    }
  }
  __syncthreads();
  // phase 2: wave w aggregates dests w*4..w*4+3; lane covers 8 of 512 cols (uint4 = 8 bf16)
  const unsigned short* featb = AB + ((size_t)(b << 12))*1024 + 512 + lane*8;
  #pragma unroll
  for (int dd = 0; dd < 4; dd++) {
    int d = w*4 + dd;
    int deg = cnt[d]; if (deg > CAP) deg = CAP;
    float inv = 1.0f / (float)(deg > 1 ? deg : 1);
    float a0=0.f,a1=0.f,a2=0.f,a3=0.f,a4=0.f,a5=0.f,a6=0.f,a7=0.f;
    for (int n = 0; n < deg; n++) {
      int j = nlist[d*CAP + n];
      uint4 v = *(const uint4*)(featb + (size_t)j*1024);
      union { unsigned u; float f; } lo, hi;
      lo.u = v.x << 16;          hi.u = v.x & 0xFFFF0000u;
      a0 += fmaxf(lo.f, 0.f);    a1 += fmaxf(hi.f, 0.f);
      lo.u = v.y << 16;          hi.u = v.y & 0xFFFF0000u;
      a2 += fmaxf(lo.f, 0.f);    a3 += fmaxf(hi.f, 0.f);
      lo.u = v.z << 16;          hi.u = v.z & 0xFFFF0000u;
      a4 += fmaxf(lo.f, 0.f);    a5 += fmaxf(hi.f, 0.f);
      lo.u = v.w << 16;          hi.u = v.w & 0xFFFF0000u;
      a6 += fmaxf(lo.f, 0.f);    a7 += fmaxf(hi.f, 0.f);
    }
    uint4 o;
    o.x = ((unsigned)f2bf(a1*inv) << 16) | f2bf(a0*inv);
    o.y = ((unsigned)f2bf(a3*inv) << 16) | f2bf(a2*inv);
    o.z = ((unsigned)f2bf(a5*inv) << 16) | f2bf(a4*inv);
    o.w = ((unsigned)f2bf(a7*inv) << 16) | f2bf(a6*inv);
    *(uint4*)(AB + (size_t)((b << 12) + dest0 + d)*1024 + lane*8) = o;
  }
}

extern "C" void kernel_launch(void* const* d_in, const int* in_sizes, int n_in,
                              void* d_out, int out_size, void* d_ws, size_t ws_size,
                              hipStream_t stream) {
  const float* images    = (const float*)d_in[0];
  const float* positions = (const float*)d_in[1];
  const float* W_feat    = (const float*)d_in[2];
  const float* b_feat    = (const float*)d_in[3];
  const float* W_pos     = (const float*)d_in[4];
  const float* W_gnn     = (const float*)d_in[5];
  const float* W_self    = (const float*)d_in[6];
  const float* anchors   = (const float*)d_in[7];
  float* out = (float*)d_out;

  char* ws = (char*)d_ws;
  unsigned short* imgs_bf = (unsigned short*)ws;                     // 16384*1536*2 = 50331648
  unsigned short* AB      = (unsigned short*)(ws + 50331648);        // 16384*1024*2 = 33554432
  unsigned short* WfT     = (unsigned short*)(ws + 83886080);        // 512*1536*2  = 1572864
  unsigned short* WgsT    = (unsigned short*)(ws + 85458944);        // 512*1024*2  = 1048576
  float*          anorm   = (float*)(ws + 86507520);                 // 8*4

  hipMemsetAsync(d_out, 0, sizeof(float)*B_*(H_+K_), stream);
  k_prep<<<dim3(8, 41), 256, 0, stream>>>(W_feat, W_gnn, W_self, anchors, WfT, WgsT, anorm);
  k_concept_cast<<<M_/32, 256, 0, stream>>>(images, anchors, anorm, imgs_bf, out);
  k_gemm<<<512, 256, 0, stream>>>(imgs_bf, WfT, D_, 0, b_feat, W_pos, positions, AB, out);
  k_aggregate<<<1024, 256, 0, stream>>>(positions, AB);
  k_gemm<<<512, 256, 0, stream>>>(AB, WgsT, 1024, 1, nullptr, nullptr, nullptr, AB, out);
}

// Round 4
// 309.468 us; speedup vs baseline: 1.2087x; 1.0282x over previous
//
#include <hip/hip_runtime.h>

#define B_ 4
#define N_ 4096
#define D_ 1536
#define H_ 512
#define K_ 8
#define M_ (B_*N_)          // 16384
#define R2_ 160000.0f       // 400^2
#define CAP 192             // max neighbors tracked per node (mean deg ~32)

typedef __attribute__((ext_vector_type(8))) short bf16x8;
typedef __attribute__((ext_vector_type(4))) float f32x4;

__device__ __forceinline__ unsigned short f2bf(float f) {
  union { float f; unsigned u; } v; v.f = f;
  unsigned r = (v.u + 0x7FFFu + ((v.u >> 16) & 1u)) >> 16;
  return (unsigned short)r;
}

typedef const __attribute__((address_space(1))) unsigned int gas_u32;
typedef __attribute__((address_space(3))) unsigned int las_u32;
__device__ __forceinline__ void gl_lds16(const unsigned short* g, unsigned short* l) {
  __builtin_amdgcn_global_load_lds((gas_u32*)g, (las_u32*)l, 16, 0, 0);
}

// ---------------- K0: prep — anchor norms + all weight transposes (one launch) ----------
__global__ __launch_bounds__(256) void k_prep(
    const float* __restrict__ Wf, const float* __restrict__ Wg, const float* __restrict__ Ws,
    const float* __restrict__ anchors, unsigned short* __restrict__ WfT,
    unsigned short* __restrict__ WgsT, float* __restrict__ anorm) {
  __shared__ float t[64][65];
  __shared__ float red[4];
  int bx = blockIdx.x, by = blockIdx.y, tid = threadIdx.x;
  if (by == 40) {
    int k = bx;
    float s = 0.f;
    for (int i = tid; i < D_; i += 256) { float v = anchors[k*D_ + i]; s += v*v; }
    #pragma unroll
    for (int off = 32; off; off >>= 1) s += __shfl_down(s, off);
    if ((tid & 63) == 0) red[tid >> 6] = s;
    __syncthreads();
    if (tid == 0) anorm[k] = fmaxf(sqrtf(red[0]+red[1]+red[2]+red[3]), 1e-12f);
    return;
  }
  const float* W; unsigned short* WT; int kt, outStride, outOff;
  if (by < 24)      { W = Wf; WT = WfT;  kt = by;      outStride = D_;   outOff = 0; }
  else if (by < 32) { W = Wg; WT = WgsT; kt = by - 24; outStride = 1024; outOff = 0; }
  else              { W = Ws; WT = WgsT; kt = by - 32; outStride = 1024; outOff = 512; }
  int tx = tid & 63, ty = tid >> 6;
  #pragma unroll
  for (int r = 0; r < 64; r += 4)
    t[ty + r][tx] = W[(size_t)(kt*64 + ty + r)*H_ + bx*64 + tx];
  __syncthreads();
  #pragma unroll
  for (int r = 0; r < 64; r += 4) {
    int n = bx*64 + ty + r;
    WT[(size_t)n*outStride + outOff + kt*64 + tx] = f2bf(t[tx][ty + r]);
  }
}

// ---------------- K1: concept scores + images f32->bf16 cast (LDS-staged anchors) ----------------
__global__ __launch_bounds__(256) void k_concept_cast(
    const float* __restrict__ images, const float* __restrict__ anchors,
    const float* __restrict__ anorm, unsigned short* __restrict__ imgs_bf,
    float* __restrict__ out) {
  __shared__ float sA[K_*D_];     // 48 KB
  __shared__ float sc[4][K_];
  int tid = threadIdx.x, lane = tid & 63, w = tid >> 6;
  {
    const float4* a4 = (const float4*)anchors;
    float4* sA4 = (float4*)sA;
    #pragma unroll
    for (int i = 0; i < 12; i++) sA4[tid + 256*i] = a4[tid + 256*i];
  }
  __syncthreads();
  float acc_k[K_] = {};
  for (int r = 0; r < 8; r++) {
    int gm = blockIdx.x*32 + w*8 + r;
    const float4* xrow = (const float4*)(images + (size_t)gm*D_);
    float nrm = 0.f; float dot[K_] = {};
    #pragma unroll
    for (int it = 0; it < 6; it++) {
      int j = lane + 64*it;
      float4 x = xrow[j];
      nrm += x.x*x.x + x.y*x.y + x.z*x.z + x.w*x.w;
      #pragma unroll
      for (int k = 0; k < K_; k++) {
        float4 a = *(const float4*)&sA[(size_t)(k*384 + j)*4];
        dot[k] += x.x*a.x + x.y*a.y + x.z*a.z + x.w*a.w;
      }
      ushort4 s;
      s.x = f2bf(x.x); s.y = f2bf(x.y); s.z = f2bf(x.z); s.w = f2bf(x.w);
      *(ushort4*)&imgs_bf[(size_t)gm*D_ + (size_t)j*4] = s;
    }
    #pragma unroll
    for (int off = 32; off; off >>= 1) {
      nrm += __shfl_down(nrm, off);
      #pragma unroll
      for (int k = 0; k < K_; k++) dot[k] += __shfl_down(dot[k], off);
    }
    if (lane == 0) {
      float inv = 1.0f / fmaxf(sqrtf(nrm), 1e-12f);
      #pragma unroll
      for (int k = 0; k < K_; k++) acc_k[k] += dot[k] * inv / anorm[k];
    }
  }
  if (lane == 0) {
    #pragma unroll
    for (int k = 0; k < K_; k++) sc[w][k] = acc_k[k];
  }
  __syncthreads();
  if (tid < K_) {
    float s = sc[0][tid] + sc[1][tid] + sc[2][tid] + sc[3][tid];
    int b = blockIdx.x >> 7;    // 128 blocks per graph
    atomicAdd(out + b*(H_+K_) + H_ + tid, s * (1.0f/N_));
  }
}

// ---------------- GEMM: C(16384 x 512) = A(16384 x Kdim) @ BT^T, m97-style staging ----------------
#define BM 128
#define BN 128
#define BK 32

__global__ __launch_bounds__(256) void k_gemm(
    const unsigned short* __restrict__ A, const unsigned short* __restrict__ BT,
    int Kdim, int mode, const float* __restrict__ bias, const float* __restrict__ Wpos,
    const float* __restrict__ positions, unsigned short* __restrict__ AB,
    float* __restrict__ out) {
  __shared__ unsigned short As[BM*BK];   // 8 KB, row-major stride 32 (unpadded: DMA layout)
  __shared__ unsigned short Bs[BN*BK];
  __shared__ float colsum[BN];
  int tid = threadIdx.x;
  int lane = tid & 63, wv = tid >> 6;
  int wm = wv >> 1, wn = wv & 1;
  int l15 = lane & 15, quad = lane >> 4;
  int bx = blockIdx.x;
  // bn-major: the 4 blocks sharing an A-tile are temporally adjacent -> L3 absorbs refetch
  int bm = bx >> 2, bn = bx & 3;
  int m0 = bm*BM, n0 = bn*BN;

  f32x4 acc[4][4] = {};

  int c = wv*2;
  int rowc = (lane >> 2), seg = lane & 3;
  const unsigned short* gA0 = A  + (size_t)(m0 + c*16 + rowc)*Kdim + seg*8;
  const unsigned short* gA1 = gA0 + (size_t)16*Kdim;
  const unsigned short* gB0 = BT + (size_t)(n0 + c*16 + rowc)*Kdim + seg*8;
  const unsigned short* gB1 = gB0 + (size_t)16*Kdim;
  unsigned short* lA0 = As + c*512;  // wave-uniform LDS base; DMA scatters lane*16B
  unsigned short* lA1 = lA0 + 512;
  unsigned short* lB0 = Bs + c*512;
  unsigned short* lB1 = lB0 + 512;

  int nk = Kdim / BK;
  for (int kt = 0; kt < nk; kt++) {
    __syncthreads();
    gl_lds16(gA0, lA0); gl_lds16(gA1, lA1);
    gl_lds16(gB0, lB0); gl_lds16(gB1, lB1);
    gA0 += BK; gA1 += BK; gB0 += BK; gB1 += BK;
    __syncthreads();

    bf16x8 aF[4], bF[4];
    #pragma unroll
    for (int f = 0; f < 4; f++)
      aF[f] = *(const bf16x8*)&As[(wm*64 + f*16 + l15)*BK + quad*8];
    #pragma unroll
    for (int f = 0; f < 4; f++)
      bF[f] = *(const bf16x8*)&Bs[(wn*64 + f*16 + l15)*BK + quad*8];
    #pragma unroll
    for (int mi = 0; mi < 4; mi++)
      #pragma unroll
      for (int ni = 0; ni < 4; ni++)
        acc[mi][ni] = __builtin_amdgcn_mfma_f32_16x16x32_bf16(aF[mi], bF[ni], acc[mi][ni], 0, 0, 0);
  }

  if (mode == 0) {
    float bz[4], w0v[4], w1v[4];
    #pragma unroll
    for (int ni = 0; ni < 4; ni++) {
      int gh = n0 + wn*64 + ni*16 + l15;
      bz[ni] = bias[gh]; w0v[ni] = Wpos[gh]; w1v[ni] = Wpos[H_ + gh];
    }
    #pragma unroll
    for (int mi = 0; mi < 4; mi++) {
      #pragma unroll
      for (int r = 0; r < 4; r++) {
        int gm = m0 + wm*64 + mi*16 + quad*4 + r;
        float2 p = ((const float2*)positions)[gm];
        #pragma unroll
        for (int ni = 0; ni < 4; ni++) {
          int gh = n0 + wn*64 + ni*16 + l15;
          float v = acc[mi][ni][r] + bz[ni] + p.x*w0v[ni] + p.y*w1v[ni];
          AB[(size_t)gm*1024 + 512 + gh] = f2bf(v);
        }
      }
    }
  } else {
    if (tid < BN) colsum[tid] = 0.f;
    __syncthreads();
    #pragma unroll
    for (int ni = 0; ni < 4; ni++) {
      float s = 0.f;
      #pragma unroll
      for (int mi = 0; mi < 4; mi++) {
        #pragma unroll
        for (int r = 0; r < 4; r++) s += fmaxf(acc[mi][ni][r], 0.f);
      }
      s += __shfl_down(s, 32);
      s += __shfl_down(s, 16);
      if (quad == 0) atomicAdd(&colsum[wn*64 + ni*16 + l15], s);
    }
    __syncthreads();
    if (tid < BN) {
      int b = m0 >> 12;
      atomicAdd(out + b*(H_+K_) + n0 + tid, colsum[tid] * (1.0f/N_));
    }
  }
}

// ---------------- K3: radius graph + mean aggregation, ILP-4 gather ----------------
__device__ __forceinline__ void acc8(uint4 v, float* a) {
  union { unsigned u; float f; } t;
  t.u = v.x << 16;          a[0] += fmaxf(t.f, 0.f);
  t.u = v.x & 0xFFFF0000u;  a[1] += fmaxf(t.f, 0.f);
  t.u = v.y << 16;          a[2] += fmaxf(t.f, 0.f);
  t.u = v.y & 0xFFFF0000u;  a[3] += fmaxf(t.f, 0.f);
  t.u = v.z << 16;          a[4] += fmaxf(t.f, 0.f);
  t.u = v.z & 0xFFFF0000u;  a[5] += fmaxf(t.f, 0.f);
  t.u = v.w << 16;          a[6] += fmaxf(t.f, 0.f);
  t.u = v.w & 0xFFFF0000u;  a[7] += fmaxf(t.f, 0.f);
}

__global__ __launch_bounds__(256) void k_aggregate(const float* __restrict__ positions,
                                                   unsigned short* __restrict__ AB) {
  __shared__ unsigned short nlist[16*CAP];
  __shared__ int cnt[16];
  __shared__ float sdx[16], sdy[16];
  int blk = blockIdx.x;                 // 0..1023
  int xcd = blk & 7;
  int b = xcd >> 1;                     // graph b pinned to XCDs {2b, 2b+1}
  int sub = ((blk >> 3) << 1) | (xcd & 1);   // 0..255
  int dest0 = sub * 16;                 // first dest node within graph
  int tid = threadIdx.x, lane = tid & 63, w = tid >> 6;
  const float2* p2 = (const float2*)(positions + (size_t)b*N_*2);
  if (tid < 16) {
    cnt[tid] = 0;
    float2 pd = p2[dest0 + tid];
    sdx[tid] = pd.x; sdy[tid] = pd.y;
  }
  __syncthreads();
  // phase 1: one scan of positions, 16 dests tested per src point
  for (int it = 0; it < 16; it++) {
    int j = tid + 256*it;
    float2 pj = p2[j];
    #pragma unroll
    for (int d = 0; d < 16; d++) {
      float dx = pj.x - sdx[d], dy = pj.y - sdy[d];
      if (dx*dx + dy*dy < R2_ && j != dest0 + d) {
        int p = atomicAdd(&cnt[d], 1);
        if (p < CAP) nlist[d*CAP + p] = (unsigned short)j;
      }
    }
  }
  __syncthreads();
  // phase 2: wave w -> dests w*4..w*4+3; lane covers 8 of 512 cols; neighbor loop ILP-4
  const unsigned short* featb = AB + ((size_t)(b << 12))*1024 + 512 + lane*8;
  #pragma unroll
  for (int dd = 0; dd < 4; dd++) {
    int d = w*4 + dd;
    int deg = cnt[d]; if (deg > CAP) deg = CAP;
    float inv = 1.0f / (float)(deg > 1 ? deg : 1);
    float a[8] = {};
    int n = 0;
    for (; n + 4 <= deg; n += 4) {
      ushort4 idx = *(const ushort4*)&nlist[d*CAP + n];  // one ds_read_b64
      uint4 v0 = *(const uint4*)(featb + (size_t)idx.x*1024);
      uint4 v1 = *(const uint4*)(featb + (size_t)idx.y*1024);
      uint4 v2 = *(const uint4*)(featb + (size_t)idx.z*1024);
      uint4 v3 = *(const uint4*)(featb + (size_t)idx.w*1024);
      acc8(v0, a); acc8(v1, a); acc8(v2, a); acc8(v3, a);
    }
    for (; n < deg; n++) {
      int j = nlist[d*CAP + n];
      uint4 v = *(const uint4*)(featb + (size_t)j*1024);
      acc8(v, a);
    }
    uint4 o;
    o.x = ((unsigned)f2bf(a[1]*inv) << 16) | f2bf(a[0]*inv);
    o.y = ((unsigned)f2bf(a[3]*inv) << 16) | f2bf(a[2]*inv);
    o.z = ((unsigned)f2bf(a[5]*inv) << 16) | f2bf(a[4]*inv);
    o.w = ((unsigned)f2bf(a[7]*inv) << 16) | f2bf(a[6]*inv);
    *(uint4*)(AB + (size_t)((b << 12) + dest0 + d)*1024 + lane*8) = o;
  }
}

extern "C" void kernel_launch(void* const* d_in, const int* in_sizes, int n_in,
                              void* d_out, int out_size, void* d_ws, size_t ws_size,
                              hipStream_t stream) {
  const float* images    = (const float*)d_in[0];
  const float* positions = (const float*)d_in[1];
  const float* W_feat    = (const float*)d_in[2];
  const float* b_feat    = (const float*)d_in[3];
  const float* W_pos     = (const float*)d_in[4];
  const float* W_gnn     = (const float*)d_in[5];
  const float* W_self    = (const float*)d_in[6];
  const float* anchors   = (const float*)d_in[7];
  float* out = (float*)d_out;

  char* ws = (char*)d_ws;
  unsigned short* imgs_bf = (unsigned short*)ws;                     // 16384*1536*2 = 50331648
  unsigned short* AB      = (unsigned short*)(ws + 50331648);        // 16384*1024*2 = 33554432
  unsigned short* WfT     = (unsigned short*)(ws + 83886080);        // 512*1536*2  = 1572864
  unsigned short* WgsT    = (unsigned short*)(ws + 85458944);        // 512*1024*2  = 1048576
  float*          anorm   = (float*)(ws + 86507520);                 // 8*4

  hipMemsetAsync(d_out, 0, sizeof(float)*B_*(H_+K_), stream);
  k_prep<<<dim3(8, 41), 256, 0, stream>>>(W_feat, W_gnn, W_self, anchors, WfT, WgsT, anorm);
  k_concept_cast<<<M_/32, 256, 0, stream>>>(images, anchors, anorm, imgs_bf, out);
  k_gemm<<<512, 256, 0, stream>>>(imgs_bf, WfT, D_, 0, b_feat, W_pos, positions, AB, out);
  k_aggregate<<<1024, 256, 0, stream>>>(positions, AB);
  k_gemm<<<512, 256, 0, stream>>>(AB, WgsT, 1024, 1, nullptr, nullptr, nullptr, AB, out);
}